// Round 1
// baseline (355.638 us; speedup 1.0000x reference)
//
#include <hip/hip_runtime.h>

// ChineseCLIP vision attention, MI355X bf16-MFMA pipeline.
// B=32, T=257, D=1024, H=16, HD=64. All GEMMs via mfma_f32_16x16x32_bf16.
// Workspace layout (bytes), total ~95.6 MB:
//   xb   [8224x1024 bf16]          @ 0
//   wq/wk/wv/wo bf16 [1024x1024]   @ ...
//   Q,K  [512][272][64] bf16  (t padded 257->272; pad rows stay poison, masked)
//   Vt   [512][64][272] bf16  (V transposed for contiguous PV B-frags)
//   ctx  [8224][1024] bf16

#define B_   32
#define T_   257
#define TP   272
#define H_   16
#define HD_  64
#define D_   1024
#define NTOK 8224
#define BH_  512

typedef __bf16 bf16;
typedef __bf16 bf16x4 __attribute__((ext_vector_type(4)));
typedef __bf16 bf16x8 __attribute__((ext_vector_type(8)));
typedef float floatx4 __attribute__((ext_vector_type(4)));

static constexpr size_t SZ_XB  = (size_t)NTOK * D_ * 2;      // 16,842,752
static constexpr size_t SZ_W   = (size_t)D_ * D_ * 2;        //  2,097,152
static constexpr size_t SZ_QK  = (size_t)BH_ * TP * HD_ * 2; // 17,825,792
static constexpr size_t SZ_CTX = (size_t)NTOK * D_ * 2;

static constexpr size_t OFF_XB  = 0;
static constexpr size_t OFF_WQ  = OFF_XB + SZ_XB;
static constexpr size_t OFF_WK  = OFF_WQ + SZ_W;
static constexpr size_t OFF_WV  = OFF_WK + SZ_W;
static constexpr size_t OFF_WO  = OFF_WV + SZ_W;
static constexpr size_t OFF_Q   = OFF_WO + SZ_W;
static constexpr size_t OFF_K   = OFF_Q  + SZ_QK;
static constexpr size_t OFF_VT  = OFF_K  + SZ_QK;
static constexpr size_t OFF_CTX = OFF_VT + SZ_QK;

// ---------------- fp32 -> bf16 cast (vectorized) ----------------
__global__ void cast_bf16_kernel(const float* __restrict__ src,
                                 bf16* __restrict__ dst, int n4) {
  int i = blockIdx.x * blockDim.x + threadIdx.x;
  int stride = gridDim.x * blockDim.x;
  for (int idx = i; idx < n4; idx += stride) {
    float4 v = reinterpret_cast<const float4*>(src)[idx];
    bf16x4 o;
    o[0] = (bf16)v.x; o[1] = (bf16)v.y; o[2] = (bf16)v.z; o[3] = (bf16)v.w;
    reinterpret_cast<bf16x4*>(dst)[idx] = o;
  }
}

// ---------------- QKV projection GEMM ----------------
// C[m,n] = sum_k xb[m,k] * W[n,k]; z = blockIdx.z selects (W, bias, layout).
// z=0: Q  -> [bh][t(272)][hd], value (acc+bias)*0.125
// z=1: K  -> [bh][t(272)][hd]
// z=2: V  -> Vt [bh][hd][t(272)]
__global__ __launch_bounds__(256) void qkv_gemm(
    const bf16* __restrict__ xb,
    const bf16* __restrict__ wq, const bf16* __restrict__ wk,
    const bf16* __restrict__ wv,
    const float* __restrict__ bq, const float* __restrict__ bk,
    const float* __restrict__ bv,
    bf16* __restrict__ Q, bf16* __restrict__ K, bf16* __restrict__ Vt) {
  __shared__ bf16 Ash[128 * 40];  // stride 40: 2-way bank conflict (free)
  __shared__ bf16 Bsh[128 * 40];

  const int z = blockIdx.z;
  const bf16* W = (z == 0) ? wq : (z == 1) ? wk : wv;
  const float* bias = (z == 0) ? bq : (z == 1) ? bk : bv;
  const int mbase = blockIdx.x * 128;
  const int nbase = blockIdx.y * 128;
  const int tid = threadIdx.x;
  const int lane = tid & 63;
  const int w = tid >> 6;
  const int wr = w >> 1, wc = w & 1;
  const int n15 = lane & 15, quad = lane >> 4;

  floatx4 acc[4][4] = {};

  const int srow = tid >> 2;  // 0..63
  const int sseg = tid & 3;   // 0..3, 8 bf16 each

  for (int k0 = 0; k0 < D_; k0 += 32) {
#pragma unroll
    for (int rr = 0; rr < 2; rr++) {
      int r = srow + rr * 64;
      int gm = mbase + r; if (gm > NTOK - 1) gm = NTOK - 1;  // clamp OOB rows
      uint4 va = *reinterpret_cast<const uint4*>(xb + (size_t)gm * D_ + k0 + sseg * 8);
      *reinterpret_cast<uint4*>(Ash + r * 40 + sseg * 8) = va;
      uint4 vb = *reinterpret_cast<const uint4*>(W + (size_t)(nbase + r) * D_ + k0 + sseg * 8);
      *reinterpret_cast<uint4*>(Bsh + r * 40 + sseg * 8) = vb;
    }
    __syncthreads();
    bf16x8 af[4], bf[4];
#pragma unroll
    for (int i = 0; i < 4; i++) {
      af[i] = *reinterpret_cast<const bf16x8*>(Ash + (wr * 64 + i * 16 + n15) * 40 + quad * 8);
      bf[i] = *reinterpret_cast<const bf16x8*>(Bsh + (wc * 64 + i * 16 + n15) * 40 + quad * 8);
    }
#pragma unroll
    for (int i = 0; i < 4; i++)
#pragma unroll
      for (int j = 0; j < 4; j++)
        acc[i][j] = __builtin_amdgcn_mfma_f32_16x16x32_bf16(af[i], bf[j], acc[i][j], 0, 0, 0);
    __syncthreads();
  }

  const float scale = (z == 0) ? 0.125f : 1.0f;
#pragma unroll
  for (int i = 0; i < 4; i++) {
    int rowb = mbase + wr * 64 + i * 16 + quad * 4;
#pragma unroll
    for (int j = 0; j < 4; j++) {
      int col = nbase + wc * 64 + j * 16 + n15;
      float bval = bias[col];
      int h = col >> 6, hd = col & 63;
#pragma unroll
      for (int r = 0; r < 4; r++) {
        int m = rowb + r;
        if (m < NTOK) {
          float v = (acc[i][j][r] + bval) * scale;
          int b = m / T_;
          int t = m - b * T_;
          int bh = b * H_ + h;
          if (z == 2)
            Vt[((size_t)bh * HD_ + hd) * TP + t] = (bf16)v;
          else {
            bf16* dst = (z == 0) ? Q : K;
            dst[((size_t)bh * TP + t) * HD_ + hd] = (bf16)v;
          }
        }
      }
    }
  }
}

// ---------------- fused attention ----------------
// block = (qtile in [0,5), bh in [0,512)); 4 waves, each 16 q-rows.
// S rows (16x272) live in 17 C-frags per wave; full-row softmax in registers;
// P -> LDS (A-layout round trip) -> PV with Vt B-frags straight from global.
__global__ __launch_bounds__(256) void attn_kernel(
    const bf16* __restrict__ Q, const bf16* __restrict__ K,
    const bf16* __restrict__ Vt, bf16* __restrict__ ctx) {
  __shared__ bf16 Pl[4 * 16 * 296];  // 37,888 B; stride 296 -> 16B aligned rows

  const int qt = blockIdx.x;
  const int bh = blockIdx.y;
  const int tid = threadIdx.x;
  const int lane = tid & 63, w = tid >> 6;
  const int n15 = lane & 15, quad = lane >> 4;

  // Q A-frags for this wave's 16 rows (row = lane&15)
  const size_t qrow = (size_t)bh * TP + qt * 64 + w * 16 + n15;
  bf16x8 aq0 = *reinterpret_cast<const bf16x8*>(Q + qrow * HD_ + quad * 8);
  bf16x8 aq1 = *reinterpret_cast<const bf16x8*>(Q + qrow * HD_ + 32 + quad * 8);

  floatx4 s[17];
#pragma unroll
  for (int kt = 0; kt < 17; kt++) {
    const size_t krow = (size_t)bh * TP + kt * 16 + n15;
    bf16x8 b0 = *reinterpret_cast<const bf16x8*>(K + krow * HD_ + quad * 8);
    bf16x8 b1 = *reinterpret_cast<const bf16x8*>(K + krow * HD_ + 32 + quad * 8);
    floatx4 c = {};
    c = __builtin_amdgcn_mfma_f32_16x16x32_bf16(aq0, b0, c, 0, 0, 0);
    c = __builtin_amdgcn_mfma_f32_16x16x32_bf16(aq1, b1, c, 0, 0, 0);
    s[kt] = c;
  }
  // mask invalid keys (only key 256 of tile 16 is valid)
  if (n15 != 0) {
#pragma unroll
    for (int r = 0; r < 4; r++) s[16][r] = -1e30f;
  }

  bf16* Prow = Pl + w * (16 * 296);

  float l[4];
#pragma unroll
  for (int r = 0; r < 4; r++) {
    float m0 = s[0][r];
#pragma unroll
    for (int kt = 1; kt < 17; kt++) m0 = fmaxf(m0, s[kt][r]);
    m0 = fmaxf(m0, __shfl_xor(m0, 1));
    m0 = fmaxf(m0, __shfl_xor(m0, 2));
    m0 = fmaxf(m0, __shfl_xor(m0, 4));
    m0 = fmaxf(m0, __shfl_xor(m0, 8));
    float sum = 0.f;
#pragma unroll
    for (int kt = 0; kt < 17; kt++) {
      float p = __expf(s[kt][r] - m0);
      sum += p;
      Prow[(quad * 4 + r) * 296 + kt * 16 + n15] = (bf16)p;
    }
    sum += __shfl_xor(sum, 1);
    sum += __shfl_xor(sum, 2);
    sum += __shfl_xor(sum, 4);
    sum += __shfl_xor(sum, 8);
    l[r] = sum;
  }
  // zero-fill P cols [272,288) so the last K=32 PV step multiplies by 0
  {
    bf16* zp = Prow + n15 * 296 + 272 + quad * 4;
    zp[0] = (bf16)0.f; zp[1] = (bf16)0.f; zp[2] = (bf16)0.f; zp[3] = (bf16)0.f;
  }
  // (wave-private LDS region: no __syncthreads needed)

  floatx4 o[4] = {};
#pragma unroll
  for (int kt2 = 0; kt2 < 9; kt2++) {
    int kk = kt2 * 32;
    bf16x8 ap = *reinterpret_cast<const bf16x8*>(Prow + n15 * 296 + kk + quad * 8);
#pragma unroll
    for (int dt = 0; dt < 4; dt++) {
      const size_t vrow = (size_t)bh * HD_ + dt * 16 + n15;
      bf16x8 vb = *reinterpret_cast<const bf16x8*>(Vt + vrow * TP + kk + quad * 8);
      o[dt] = __builtin_amdgcn_mfma_f32_16x16x32_bf16(ap, vb, o[dt], 0, 0, 0);
    }
  }

  const int b = bh >> 4, h = bh & 15;
#pragma unroll
  for (int r = 0; r < 4; r++) {
    int q = qt * 64 + w * 16 + quad * 4 + r;
    if (q < T_) {
      float inv = 1.0f / l[r];
      size_t base = ((size_t)(b * T_ + q)) * D_ + h * 64;
#pragma unroll
      for (int dt = 0; dt < 4; dt++)
        ctx[base + dt * 16 + n15] = (bf16)(o[dt][r] * inv);
    }
  }
}

// ---------------- output projection GEMM (fp32 out) ----------------
__global__ __launch_bounds__(256) void o_gemm(
    const bf16* __restrict__ ctx, const bf16* __restrict__ wo,
    const float* __restrict__ bo, float* __restrict__ out) {
  __shared__ bf16 Ash[128 * 40];
  __shared__ bf16 Bsh[128 * 40];

  const int mbase = blockIdx.x * 128;
  const int nbase = blockIdx.y * 128;
  const int tid = threadIdx.x;
  const int lane = tid & 63;
  const int w = tid >> 6;
  const int wr = w >> 1, wc = w & 1;
  const int n15 = lane & 15, quad = lane >> 4;

  floatx4 acc[4][4] = {};
  const int srow = tid >> 2;
  const int sseg = tid & 3;

  for (int k0 = 0; k0 < D_; k0 += 32) {
#pragma unroll
    for (int rr = 0; rr < 2; rr++) {
      int r = srow + rr * 64;
      int gm = mbase + r; if (gm > NTOK - 1) gm = NTOK - 1;
      uint4 va = *reinterpret_cast<const uint4*>(ctx + (size_t)gm * D_ + k0 + sseg * 8);
      *reinterpret_cast<uint4*>(Ash + r * 40 + sseg * 8) = va;
      uint4 vb = *reinterpret_cast<const uint4*>(wo + (size_t)(nbase + r) * D_ + k0 + sseg * 8);
      *reinterpret_cast<uint4*>(Bsh + r * 40 + sseg * 8) = vb;
    }
    __syncthreads();
    bf16x8 af[4], bf[4];
#pragma unroll
    for (int i = 0; i < 4; i++) {
      af[i] = *reinterpret_cast<const bf16x8*>(Ash + (wr * 64 + i * 16 + n15) * 40 + quad * 8);
      bf[i] = *reinterpret_cast<const bf16x8*>(Bsh + (wc * 64 + i * 16 + n15) * 40 + quad * 8);
    }
#pragma unroll
    for (int i = 0; i < 4; i++)
#pragma unroll
      for (int j = 0; j < 4; j++)
        acc[i][j] = __builtin_amdgcn_mfma_f32_16x16x32_bf16(af[i], bf[j], acc[i][j], 0, 0, 0);
    __syncthreads();
  }

#pragma unroll
  for (int i = 0; i < 4; i++) {
    int rowb = mbase + wr * 64 + i * 16 + quad * 4;
#pragma unroll
    for (int j = 0; j < 4; j++) {
      int col = nbase + wc * 64 + j * 16 + n15;
      float bval = bo[col];
#pragma unroll
      for (int r = 0; r < 4; r++) {
        int m = rowb + r;
        if (m < NTOK) out[(size_t)m * D_ + col] = acc[i][j][r] + bval;
      }
    }
  }
}

extern "C" void kernel_launch(void* const* d_in, const int* in_sizes, int n_in,
                              void* d_out, int out_size, void* d_ws, size_t ws_size,
                              hipStream_t stream) {
  const float* hs = (const float*)d_in[0];
  const float* Wq = (const float*)d_in[1];
  const float* bq = (const float*)d_in[2];
  const float* Wk = (const float*)d_in[3];
  const float* bk = (const float*)d_in[4];
  const float* Wv = (const float*)d_in[5];
  const float* bv = (const float*)d_in[6];
  const float* Wo = (const float*)d_in[7];
  const float* bo = (const float*)d_in[8];

  char* ws = (char*)d_ws;
  bf16* xb  = (bf16*)(ws + OFF_XB);
  bf16* wqb = (bf16*)(ws + OFF_WQ);
  bf16* wkb = (bf16*)(ws + OFF_WK);
  bf16* wvb = (bf16*)(ws + OFF_WV);
  bf16* wob = (bf16*)(ws + OFF_WO);
  bf16* Qw  = (bf16*)(ws + OFF_Q);
  bf16* Kw  = (bf16*)(ws + OFF_K);
  bf16* Vtw = (bf16*)(ws + OFF_VT);
  bf16* ctx = (bf16*)(ws + OFF_CTX);

  cast_bf16_kernel<<<2048, 256, 0, stream>>>(hs, xb, NTOK * D_ / 4);
  cast_bf16_kernel<<<1024, 256, 0, stream>>>(Wq, wqb, D_ * D_ / 4);
  cast_bf16_kernel<<<1024, 256, 0, stream>>>(Wk, wkb, D_ * D_ / 4);
  cast_bf16_kernel<<<1024, 256, 0, stream>>>(Wv, wvb, D_ * D_ / 4);
  cast_bf16_kernel<<<1024, 256, 0, stream>>>(Wo, wob, D_ * D_ / 4);

  qkv_gemm<<<dim3(65, 8, 3), 256, 0, stream>>>(xb, wqb, wkb, wvb, bq, bk, bv,
                                               Qw, Kw, Vtw);
  attn_kernel<<<dim3(5, BH_), 256, 0, stream>>>(Qw, Kw, Vtw, ctx);
  o_gemm<<<dim3(65, 8), 256, 0, stream>>>(ctx, wob, bo, (float*)d_out);
}

// Round 2
// 317.116 us; speedup vs baseline: 1.1215x; 1.1215x over previous
//
#include <hip/hip_runtime.h>

// ChineseCLIP vision attention, MI355X bf16-MFMA pipeline. Round 2:
//  - fused QKV GEMM (N=3072) with m97-style global_load_lds(16B) staging
//  - grid ordered n-fastest so consecutive blocks share the A-tile (L2 reuse)
//  - o_gemm gets the same treatment; weight casts fused into one launch
// B=32, T=257, D=1024, H=16, HD=64.

#define B_   32
#define T_   257
#define TP   272
#define H_   16
#define HD_  64
#define D_   1024
#define NTOK 8224
#define BH_  512

typedef __bf16 bf16;
typedef __bf16 bf16x4 __attribute__((ext_vector_type(4)));
typedef __bf16 bf16x8 __attribute__((ext_vector_type(8)));
typedef float floatx4 __attribute__((ext_vector_type(4)));

static constexpr size_t SZ_XB   = (size_t)NTOK * D_ * 2;      // 16,842,752
static constexpr size_t SZ_WQKV = (size_t)3 * D_ * D_ * 2;    //  6,291,456
static constexpr size_t SZ_W    = (size_t)D_ * D_ * 2;        //  2,097,152
static constexpr size_t SZ_QK   = (size_t)BH_ * TP * HD_ * 2; // 17,825,792
static constexpr size_t SZ_CTX  = (size_t)NTOK * D_ * 2;

static constexpr size_t OFF_XB   = 0;
static constexpr size_t OFF_WQKV = OFF_XB + SZ_XB;
static constexpr size_t OFF_WO   = OFF_WQKV + SZ_WQKV;
static constexpr size_t OFF_Q    = OFF_WO + SZ_W;
static constexpr size_t OFF_K    = OFF_Q + SZ_QK;
static constexpr size_t OFF_VT   = OFF_K + SZ_QK;
static constexpr size_t OFF_CTX  = OFF_VT + SZ_QK;

// async global->LDS, 16B per lane; lds base must be wave-uniform
#define GLD16(gp, lp)                                                        \
  __builtin_amdgcn_global_load_lds(                                          \
      (const __attribute__((address_space(1))) void*)(gp),                   \
      (__attribute__((address_space(3))) void*)(lp), 16, 0, 0)

// ---------------- fp32 -> bf16 casts ----------------
__global__ void cast_bf16_kernel(const float* __restrict__ src,
                                 bf16* __restrict__ dst, int n4) {
  int i = blockIdx.x * blockDim.x + threadIdx.x;
  int stride = gridDim.x * blockDim.x;
  for (int idx = i; idx < n4; idx += stride) {
    float4 v = reinterpret_cast<const float4*>(src)[idx];
    bf16x4 o;
    o[0] = (bf16)v.x; o[1] = (bf16)v.y; o[2] = (bf16)v.z; o[3] = (bf16)v.w;
    reinterpret_cast<bf16x4*>(dst)[idx] = o;
  }
}

// one launch for all 4 weight matrices (blockIdx.y selects)
__global__ void cast4_kernel(const float* __restrict__ s0, const float* __restrict__ s1,
                             const float* __restrict__ s2, const float* __restrict__ s3,
                             bf16* __restrict__ d0, bf16* __restrict__ d1,
                             bf16* __restrict__ d2, bf16* __restrict__ d3, int n4) {
  const float* s = (blockIdx.y == 0) ? s0 : (blockIdx.y == 1) ? s1
                   : (blockIdx.y == 2) ? s2 : s3;
  bf16* d = (blockIdx.y == 0) ? d0 : (blockIdx.y == 1) ? d1
            : (blockIdx.y == 2) ? d2 : d3;
  int i = blockIdx.x * blockDim.x + threadIdx.x;
  int stride = gridDim.x * blockDim.x;
  for (int idx = i; idx < n4; idx += stride) {
    float4 v = reinterpret_cast<const float4*>(s)[idx];
    bf16x4 o;
    o[0] = (bf16)v.x; o[1] = (bf16)v.y; o[2] = (bf16)v.z; o[3] = (bf16)v.w;
    reinterpret_cast<bf16x4*>(d)[idx] = o;
  }
}

// ---------------- fused QKV GEMM (m97 structure) ----------------
// C[m,n] = sum_k xb[m,k] * Wqkv[n,k], n in [0,3072).
// grid = (24, 65): blockIdx.x = n-tile (fastest -> A-tile L2 reuse), y = m-tile.
// n-tile 0..7 -> Q [bh][t(272)][hd] scaled 0.125; 8..15 -> K; 16..23 -> Vt.
__global__ __launch_bounds__(256) void qkv_gemm(
    const bf16* __restrict__ xb, const bf16* __restrict__ wqkv,
    const float* __restrict__ bq, const float* __restrict__ bk,
    const float* __restrict__ bv,
    bf16* __restrict__ Q, bf16* __restrict__ K, bf16* __restrict__ Vt) {
  __shared__ bf16 Ash[128 * 32];  // unpadded: required by global_load_lds
  __shared__ bf16 Bsh[128 * 32];

  const int nbg = blockIdx.x * 128;   // global n base in [0,3072)
  const int mbase = blockIdx.y * 128;
  const int tid = threadIdx.x;
  const int lane = tid & 63;
  const int w = tid >> 6;
  const int wr = w >> 1, wc = w & 1;
  const int n15 = lane & 15, quad = lane >> 4;

  const int lrow = lane >> 2;          // 0..15 within a 16-row staging call
  const int lseg = (lane & 3) * 8;     // bf16 element offset of the 16B chunk

  floatx4 acc[4][4] = {};

  for (int k0 = 0; k0 < D_; k0 += 32) {
#pragma unroll
    for (int c = 0; c < 2; c++) {
      int r0 = w * 32 + c * 16;
      int row = r0 + lrow;
      int gm = mbase + row; if (gm > NTOK - 1) gm = NTOK - 1;
      GLD16(xb + (size_t)gm * D_ + k0 + lseg, Ash + r0 * 32);
      GLD16(wqkv + (size_t)(nbg + row) * D_ + k0 + lseg, Bsh + r0 * 32);
    }
    __syncthreads();
    bf16x8 af[4], bfr[4];
#pragma unroll
    for (int i = 0; i < 4; i++) {
      af[i]  = *reinterpret_cast<const bf16x8*>(Ash + (wr * 64 + i * 16 + n15) * 32 + quad * 8);
      bfr[i] = *reinterpret_cast<const bf16x8*>(Bsh + (wc * 64 + i * 16 + n15) * 32 + quad * 8);
    }
#pragma unroll
    for (int i = 0; i < 4; i++)
#pragma unroll
      for (int j = 0; j < 4; j++)
        acc[i][j] = __builtin_amdgcn_mfma_f32_16x16x32_bf16(af[i], bfr[j], acc[i][j], 0, 0, 0);
    __syncthreads();
  }

#pragma unroll
  for (int i = 0; i < 4; i++) {
    int rowb = mbase + wr * 64 + i * 16 + quad * 4;
#pragma unroll
    for (int j = 0; j < 4; j++) {
      int nc = nbg + wc * 64 + j * 16 + n15;   // [0,3072)
      int z = nc >> 10;                        // 0=Q 1=K 2=V
      int col = nc & 1023;
      float bval = (z == 0) ? bq[col] : (z == 1) ? bk[col] : bv[col];
      float scale = (z == 0) ? 0.125f : 1.0f;
      int h = col >> 6, hd = col & 63;
#pragma unroll
      for (int r = 0; r < 4; r++) {
        int m = rowb + r;
        if (m < NTOK) {
          float v = (acc[i][j][r] + bval) * scale;
          int b = m / T_;
          int t = m - b * T_;
          int bh = b * H_ + h;
          if (z == 2)
            Vt[((size_t)bh * HD_ + hd) * TP + t] = (bf16)v;
          else {
            bf16* dst = (z == 0) ? Q : K;
            dst[((size_t)bh * TP + t) * HD_ + hd] = (bf16)v;
          }
        }
      }
    }
  }
}

// ---------------- fused attention ----------------
__global__ __launch_bounds__(256) void attn_kernel(
    const bf16* __restrict__ Q, const bf16* __restrict__ K,
    const bf16* __restrict__ Vt, bf16* __restrict__ ctx) {
  __shared__ bf16 Pl[4 * 16 * 296];

  const int qt = blockIdx.x;
  const int bh = blockIdx.y;
  const int tid = threadIdx.x;
  const int lane = tid & 63, w = tid >> 6;
  const int n15 = lane & 15, quad = lane >> 4;

  const size_t qrow = (size_t)bh * TP + qt * 64 + w * 16 + n15;
  bf16x8 aq0 = *reinterpret_cast<const bf16x8*>(Q + qrow * HD_ + quad * 8);
  bf16x8 aq1 = *reinterpret_cast<const bf16x8*>(Q + qrow * HD_ + 32 + quad * 8);

  floatx4 s[17];
#pragma unroll
  for (int kt = 0; kt < 17; kt++) {
    const size_t krow = (size_t)bh * TP + kt * 16 + n15;
    bf16x8 b0 = *reinterpret_cast<const bf16x8*>(K + krow * HD_ + quad * 8);
    bf16x8 b1 = *reinterpret_cast<const bf16x8*>(K + krow * HD_ + 32 + quad * 8);
    floatx4 c = {};
    c = __builtin_amdgcn_mfma_f32_16x16x32_bf16(aq0, b0, c, 0, 0, 0);
    c = __builtin_amdgcn_mfma_f32_16x16x32_bf16(aq1, b1, c, 0, 0, 0);
    s[kt] = c;
  }
  if (n15 != 0) {
#pragma unroll
    for (int r = 0; r < 4; r++) s[16][r] = -1e30f;
  }

  bf16* Prow = Pl + w * (16 * 296);

  float l[4];
#pragma unroll
  for (int r = 0; r < 4; r++) {
    float m0 = s[0][r];
#pragma unroll
    for (int kt = 1; kt < 17; kt++) m0 = fmaxf(m0, s[kt][r]);
    m0 = fmaxf(m0, __shfl_xor(m0, 1));
    m0 = fmaxf(m0, __shfl_xor(m0, 2));
    m0 = fmaxf(m0, __shfl_xor(m0, 4));
    m0 = fmaxf(m0, __shfl_xor(m0, 8));
    float sum = 0.f;
#pragma unroll
    for (int kt = 0; kt < 17; kt++) {
      float p = __expf(s[kt][r] - m0);
      sum += p;
      Prow[(quad * 4 + r) * 296 + kt * 16 + n15] = (bf16)p;
    }
    sum += __shfl_xor(sum, 1);
    sum += __shfl_xor(sum, 2);
    sum += __shfl_xor(sum, 4);
    sum += __shfl_xor(sum, 8);
    l[r] = sum;
  }
  {
    bf16* zp = Prow + n15 * 296 + 272 + quad * 4;
    zp[0] = (bf16)0.f; zp[1] = (bf16)0.f; zp[2] = (bf16)0.f; zp[3] = (bf16)0.f;
  }

  floatx4 o[4] = {};
#pragma unroll
  for (int kt2 = 0; kt2 < 9; kt2++) {
    int kk = kt2 * 32;
    bf16x8 ap = *reinterpret_cast<const bf16x8*>(Prow + n15 * 296 + kk + quad * 8);
#pragma unroll
    for (int dt = 0; dt < 4; dt++) {
      const size_t vrow = (size_t)bh * HD_ + dt * 16 + n15;
      bf16x8 vb = *reinterpret_cast<const bf16x8*>(Vt + vrow * TP + kk + quad * 8);
      o[dt] = __builtin_amdgcn_mfma_f32_16x16x32_bf16(ap, vb, o[dt], 0, 0, 0);
    }
  }

  const int b = bh >> 4, h = bh & 15;
#pragma unroll
  for (int r = 0; r < 4; r++) {
    int q = qt * 64 + w * 16 + quad * 4 + r;
    if (q < T_) {
      float inv = 1.0f / l[r];
      size_t base = ((size_t)(b * T_ + q)) * D_ + h * 64;
#pragma unroll
      for (int dt = 0; dt < 4; dt++)
        ctx[base + dt * 16 + n15] = (bf16)(o[dt][r] * inv);
    }
  }
}

// ---------------- output projection GEMM (fp32 out, m97 structure) ----------------
// grid = (8, 65): n-fastest for ctx A-tile reuse.
__global__ __launch_bounds__(256) void o_gemm(
    const bf16* __restrict__ ctx, const bf16* __restrict__ wo,
    const float* __restrict__ bo, float* __restrict__ out) {
  __shared__ bf16 Ash[128 * 32];
  __shared__ bf16 Bsh[128 * 32];

  const int nbase = blockIdx.x * 128;
  const int mbase = blockIdx.y * 128;
  const int tid = threadIdx.x;
  const int lane = tid & 63;
  const int w = tid >> 6;
  const int wr = w >> 1, wc = w & 1;
  const int n15 = lane & 15, quad = lane >> 4;

  const int lrow = lane >> 2;
  const int lseg = (lane & 3) * 8;

  floatx4 acc[4][4] = {};

  for (int k0 = 0; k0 < D_; k0 += 32) {
#pragma unroll
    for (int c = 0; c < 2; c++) {
      int r0 = w * 32 + c * 16;
      int row = r0 + lrow;
      int gm = mbase + row; if (gm > NTOK - 1) gm = NTOK - 1;
      GLD16(ctx + (size_t)gm * D_ + k0 + lseg, Ash + r0 * 32);
      GLD16(wo + (size_t)(nbase + row) * D_ + k0 + lseg, Bsh + r0 * 32);
    }
    __syncthreads();
    bf16x8 af[4], bfr[4];
#pragma unroll
    for (int i = 0; i < 4; i++) {
      af[i]  = *reinterpret_cast<const bf16x8*>(Ash + (wr * 64 + i * 16 + n15) * 32 + quad * 8);
      bfr[i] = *reinterpret_cast<const bf16x8*>(Bsh + (wc * 64 + i * 16 + n15) * 32 + quad * 8);
    }
#pragma unroll
    for (int i = 0; i < 4; i++)
#pragma unroll
      for (int j = 0; j < 4; j++)
        acc[i][j] = __builtin_amdgcn_mfma_f32_16x16x32_bf16(af[i], bfr[j], acc[i][j], 0, 0, 0);
    __syncthreads();
  }

#pragma unroll
  for (int i = 0; i < 4; i++) {
    int rowb = mbase + wr * 64 + i * 16 + quad * 4;
#pragma unroll
    for (int j = 0; j < 4; j++) {
      int col = nbase + wc * 64 + j * 16 + n15;
      float bval = bo[col];
#pragma unroll
      for (int r = 0; r < 4; r++) {
        int m = rowb + r;
        if (m < NTOK) out[(size_t)m * D_ + col] = acc[i][j][r] + bval;
      }
    }
  }
}

extern "C" void kernel_launch(void* const* d_in, const int* in_sizes, int n_in,
                              void* d_out, int out_size, void* d_ws, size_t ws_size,
                              hipStream_t stream) {
  const float* hs = (const float*)d_in[0];
  const float* Wq = (const float*)d_in[1];
  const float* bq = (const float*)d_in[2];
  const float* Wk = (const float*)d_in[3];
  const float* bk = (const float*)d_in[4];
  const float* Wv = (const float*)d_in[5];
  const float* bv = (const float*)d_in[6];
  const float* Wo = (const float*)d_in[7];
  const float* bo = (const float*)d_in[8];

  char* ws = (char*)d_ws;
  bf16* xb   = (bf16*)(ws + OFF_XB);
  bf16* wqkv = (bf16*)(ws + OFF_WQKV);
  bf16* wob  = (bf16*)(ws + OFF_WO);
  bf16* Qw   = (bf16*)(ws + OFF_Q);
  bf16* Kw   = (bf16*)(ws + OFF_K);
  bf16* Vtw  = (bf16*)(ws + OFF_VT);
  bf16* ctx  = (bf16*)(ws + OFF_CTX);

  cast_bf16_kernel<<<2048, 256, 0, stream>>>(hs, xb, NTOK * D_ / 4);
  cast4_kernel<<<dim3(256, 4), 256, 0, stream>>>(
      Wq, Wk, Wv, Wo,
      wqkv, wqkv + (size_t)D_ * D_, wqkv + (size_t)2 * D_ * D_, wob,
      D_ * D_ / 4);

  qkv_gemm<<<dim3(24, 65), 256, 0, stream>>>(xb, wqkv, bq, bk, bv, Qw, Kw, Vtw);
  attn_kernel<<<dim3(5, BH_), 256, 0, stream>>>(Qw, Kw, Vtw, ctx);
  o_gemm<<<dim3(8, 65), 256, 0, stream>>>(ctx, wob, bo, (float*)d_out);
}

// Round 3
// 270.075 us; speedup vs baseline: 1.3168x; 1.1742x over previous
//
#include <hip/hip_runtime.h>

// ChineseCLIP vision attention, MI355X bf16-MFMA pipeline. Round 3:
//  - Q/K/V stored in FRAGMENT-MAJOR layouts by the qkv epilogue so every
//    attention MFMA fragment load is one fully-coalesced wave load.
//  - attention computes S^T = K*Q^T; its C-frags are exactly the B-operand
//    layout of mfma_f32_16x16x16_bf16, so P feeds PV (O^T = V^T * P^T)
//    straight from registers: no LDS at all in the attention kernel.
//  - XCD-residency swizzle on both projection GEMMs.
// B=32, T=257, D=1024, H=16, HD=64.

#define B_   32
#define T_   257
#define TP   272
#define H_   16
#define HD_  64
#define D_   1024
#define NTOK 8224
#define BH_  512
#define FRAG_PER_BH 17408   // TP*HD elements per (b,h) in frag-major arrays

typedef __bf16 bf16;
typedef __bf16 bf16x4 __attribute__((ext_vector_type(4)));
typedef __bf16 bf16x8 __attribute__((ext_vector_type(8)));
typedef short  s16x4  __attribute__((ext_vector_type(4)));
typedef float  floatx4 __attribute__((ext_vector_type(4)));

static constexpr size_t SZ_XB   = (size_t)NTOK * D_ * 2;
static constexpr size_t SZ_WQKV = (size_t)3 * D_ * D_ * 2;
static constexpr size_t SZ_W    = (size_t)D_ * D_ * 2;
static constexpr size_t SZ_QK   = (size_t)BH_ * FRAG_PER_BH * 2;
static constexpr size_t SZ_CTX  = (size_t)NTOK * D_ * 2;

static constexpr size_t OFF_XB   = 0;
static constexpr size_t OFF_WQKV = OFF_XB + SZ_XB;
static constexpr size_t OFF_WO   = OFF_WQKV + SZ_WQKV;
static constexpr size_t OFF_Q    = OFF_WO + SZ_W;
static constexpr size_t OFF_K    = OFF_Q + SZ_QK;
static constexpr size_t OFF_V    = OFF_K + SZ_QK;
static constexpr size_t OFF_CTX  = OFF_V + SZ_QK;

#define GLD16(gp, lp)                                                        \
  __builtin_amdgcn_global_load_lds(                                          \
      (const __attribute__((address_space(1))) void*)(gp),                   \
      (__attribute__((address_space(3))) void*)(lp), 16, 0, 0)

// ---------------- fp32 -> bf16 casts ----------------
__global__ void cast_bf16_kernel(const float* __restrict__ src,
                                 bf16* __restrict__ dst, int n4) {
  int i = blockIdx.x * blockDim.x + threadIdx.x;
  int stride = gridDim.x * blockDim.x;
  for (int idx = i; idx < n4; idx += stride) {
    float4 v = reinterpret_cast<const float4*>(src)[idx];
    bf16x4 o;
    o[0] = (bf16)v.x; o[1] = (bf16)v.y; o[2] = (bf16)v.z; o[3] = (bf16)v.w;
    reinterpret_cast<bf16x4*>(dst)[idx] = o;
  }
}

__global__ void cast4_kernel(const float* __restrict__ s0, const float* __restrict__ s1,
                             const float* __restrict__ s2, const float* __restrict__ s3,
                             bf16* __restrict__ d0, bf16* __restrict__ d1,
                             bf16* __restrict__ d2, bf16* __restrict__ d3, int n4) {
  const float* s = (blockIdx.y == 0) ? s0 : (blockIdx.y == 1) ? s1
                   : (blockIdx.y == 2) ? s2 : s3;
  bf16* d = (blockIdx.y == 0) ? d0 : (blockIdx.y == 1) ? d1
            : (blockIdx.y == 2) ? d2 : d3;
  int i = blockIdx.x * blockDim.x + threadIdx.x;
  int stride = gridDim.x * blockDim.x;
  for (int idx = i; idx < n4; idx += stride) {
    float4 v = reinterpret_cast<const float4*>(s)[idx];
    bf16x4 o;
    o[0] = (bf16)v.x; o[1] = (bf16)v.y; o[2] = (bf16)v.z; o[3] = (bf16)v.w;
    reinterpret_cast<bf16x4*>(d)[idx] = o;
  }
}

// Frag-major index helpers (element offsets within one bh's 17408 elems).
// Q/K (A/B-operand of 16x16x32): [kt(17)][c(8)][ki(16)][8]; c=d/8, ki=t%16.
__device__ __forceinline__ int qk_frag_idx(int t, int d) {
  return ((t >> 4) * 8 + (d >> 3)) * 128 + (t & 15) * 8 + (d & 7);
}
// V (A-operand of 16x16x16, m=d k=key): [kt(17)][dt(4)][q2(4)][d16(16)][ki(4)]
__device__ __forceinline__ int v_frag_idx(int t, int d) {
  return ((t >> 4) * 4 + (d >> 4)) * 256 + ((t >> 2) & 3) * 64 + (d & 15) * 4 + (t & 3);
}

// ---------------- fused QKV GEMM ----------------
// grid 1D 1560 blocks; swizzle: XCD x owns n-tiles {3x..3x+2} (L2-resident B).
__global__ __launch_bounds__(256) void qkv_gemm(
    const bf16* __restrict__ xb, const bf16* __restrict__ wqkv,
    const float* __restrict__ bq, const float* __restrict__ bk,
    const float* __restrict__ bv,
    bf16* __restrict__ Qf, bf16* __restrict__ Kf, bf16* __restrict__ Vf) {
  __shared__ bf16 Ash[128 * 32];
  __shared__ bf16 Bsh[128 * 32];

  const int linear = blockIdx.x;
  const int nbg = ((linear & 7) * 3 + ((linear >> 3) % 3)) * 128;
  const int mbase = (linear / 24) * 128;
  const int tid = threadIdx.x;
  const int lane = tid & 63;
  const int w = tid >> 6;
  const int wr = w >> 1, wc = w & 1;
  const int n15 = lane & 15, quad = lane >> 4;

  const int lrow = lane >> 2;
  const int lseg = (lane & 3) * 8;

  floatx4 acc[4][4] = {};

  for (int k0 = 0; k0 < D_; k0 += 32) {
#pragma unroll
    for (int c = 0; c < 2; c++) {
      int r0 = w * 32 + c * 16;
      int row = r0 + lrow;
      int gm = mbase + row; if (gm > NTOK - 1) gm = NTOK - 1;
      GLD16(xb + (size_t)gm * D_ + k0 + lseg, Ash + r0 * 32);
      GLD16(wqkv + (size_t)(nbg + row) * D_ + k0 + lseg, Bsh + r0 * 32);
    }
    __syncthreads();
    bf16x8 af[4], bfr[4];
#pragma unroll
    for (int i = 0; i < 4; i++) {
      af[i]  = *reinterpret_cast<const bf16x8*>(Ash + (wr * 64 + i * 16 + n15) * 32 + quad * 8);
      bfr[i] = *reinterpret_cast<const bf16x8*>(Bsh + (wc * 64 + i * 16 + n15) * 32 + quad * 8);
    }
#pragma unroll
    for (int i = 0; i < 4; i++)
#pragma unroll
      for (int j = 0; j < 4; j++)
        acc[i][j] = __builtin_amdgcn_mfma_f32_16x16x32_bf16(af[i], bfr[j], acc[i][j], 0, 0, 0);
    __syncthreads();
  }

#pragma unroll
  for (int i = 0; i < 4; i++) {
    int rowb = mbase + wr * 64 + i * 16 + quad * 4;
#pragma unroll
    for (int j = 0; j < 4; j++) {
      int nc = nbg + wc * 64 + j * 16 + n15;
      int z = nc >> 10;                      // 0=Q 1=K 2=V
      int col = nc & 1023;
      float bval = (z == 0) ? bq[col] : (z == 1) ? bk[col] : bv[col];
      float scale = (z == 0) ? 0.125f : 1.0f;
      int h = col >> 6, hd = col & 63;
#pragma unroll
      for (int r = 0; r < 4; r++) {
        int m = rowb + r;
        if (m < NTOK) {
          float v = (acc[i][j][r] + bval) * scale;
          int b = m / T_;
          int t = m - b * T_;
          size_t base = (size_t)(b * H_ + h) * FRAG_PER_BH;
          if (z == 2)
            Vf[base + v_frag_idx(t, hd)] = (bf16)v;
          else {
            bf16* dst = (z == 0) ? Qf : Kf;
            dst[base + qk_frag_idx(t, hd)] = (bf16)v;
          }
        }
      }
    }
  }
}

// ---------------- fused attention (register-resident, zero LDS) ----------------
// grid = 512 (one block per bh), 4 waves; wave w handles q-tiles w, w+4, ...
// S^T = MFMA(A=K, B=Q) -> C-frag (key=quad*4+r, query=n15); softmax in-lane;
// P^T C-frags ARE the B-operand of mfma 16x16x16 -> O^T = V^T * P^T.
__global__ __launch_bounds__(256) void attn_kernel(
    const bf16* __restrict__ Qf, const bf16* __restrict__ Kf,
    const bf16* __restrict__ Vf, bf16* __restrict__ ctx) {
  const int bh = blockIdx.x;
  const int tid = threadIdx.x;
  const int lane = tid & 63, w = tid >> 6;
  const int n15 = lane & 15, quad = lane >> 4;
  const int b = bh >> 4, h = bh & 15;

  const bf16* Qb = Qf + (size_t)bh * FRAG_PER_BH;
  const bf16* Kb = Kf + (size_t)bh * FRAG_PER_BH;
  const bf16* Vb = Vf + (size_t)bh * FRAG_PER_BH;
  const int fo = quad * 128 + n15 * 8;  // lane's 16B chunk in a K/Q frag block
  const int vo = quad * 64 + n15 * 4;   // lane's 8B chunk in a V frag block

  for (int qt = w; qt < 17; qt += 4) {
    bf16x8 qb0 = *reinterpret_cast<const bf16x8*>(Qb + qt * 1024 + fo);
    bf16x8 qb1 = *reinterpret_cast<const bf16x8*>(Qb + qt * 1024 + 512 + fo);

    floatx4 s[17];
#pragma unroll
    for (int kt = 0; kt < 17; kt++) {
      bf16x8 ka0 = *reinterpret_cast<const bf16x8*>(Kb + kt * 1024 + fo);
      bf16x8 ka1 = *reinterpret_cast<const bf16x8*>(Kb + kt * 1024 + 512 + fo);
      floatx4 c = {};
      c = __builtin_amdgcn_mfma_f32_16x16x32_bf16(ka0, qb0, c, 0, 0, 0);
      c = __builtin_amdgcn_mfma_f32_16x16x32_bf16(ka1, qb1, c, 0, 0, 0);
      s[kt] = c;
    }
    // keys 257..271 invalid: tile 16 holds keys 256+quad*4+r; only 256 valid
    s[16][1] = -1e30f; s[16][2] = -1e30f; s[16][3] = -1e30f;
    if (quad != 0) s[16][0] = -1e30f;

    float m0 = -1e30f;
#pragma unroll
    for (int kt = 0; kt < 17; kt++)
#pragma unroll
      for (int r = 0; r < 4; r++) m0 = fmaxf(m0, s[kt][r]);
    m0 = fmaxf(m0, __shfl_xor(m0, 16));
    m0 = fmaxf(m0, __shfl_xor(m0, 32));

    float sum = 0.f;
    s16x4 pb[17];
#pragma unroll
    for (int kt = 0; kt < 17; kt++) {
      bf16x4 ph;
#pragma unroll
      for (int r = 0; r < 4; r++) {
        float p = __expf(s[kt][r] - m0);
        sum += p;
        ph[r] = (bf16)p;
      }
      pb[kt] = __builtin_bit_cast(s16x4, ph);
    }
    sum += __shfl_xor(sum, 16);
    sum += __shfl_xor(sum, 32);

    floatx4 o[4] = {};
#pragma unroll
    for (int kt = 0; kt < 17; kt++) {
#pragma unroll
      for (int dt = 0; dt < 4; dt++) {
        s16x4 va = *reinterpret_cast<const s16x4*>(Vb + (kt * 4 + dt) * 256 + vo);
        o[dt] = __builtin_amdgcn_mfma_f32_16x16x16bf16_1k(va, pb[kt], o[dt], 0, 0, 0);
      }
    }

    int q = qt * 16 + n15;
    if (q < T_) {
      float inv = 1.0f / sum;
      size_t ob = ((size_t)(b * T_ + q)) * D_ + h * 64 + quad * 4;
#pragma unroll
      for (int dt = 0; dt < 4; dt++) {
        bf16x4 ov;
#pragma unroll
        for (int r = 0; r < 4; r++) ov[r] = (bf16)(o[dt][r] * inv);
        *reinterpret_cast<bf16x4*>(ctx + ob + dt * 16) = ov;
      }
    }
  }
}

// ---------------- output projection GEMM (fp32 out) ----------------
__global__ __launch_bounds__(256) void o_gemm(
    const bf16* __restrict__ ctx, const bf16* __restrict__ wo,
    const float* __restrict__ bo, float* __restrict__ out) {
  __shared__ bf16 Ash[128 * 32];
  __shared__ bf16 Bsh[128 * 32];

  const int linear = blockIdx.x;
  const int nbase = (linear & 7) * 128;   // XCD x owns one B-tile
  const int mbase = (linear >> 3) * 128;
  const int tid = threadIdx.x;
  const int lane = tid & 63;
  const int w = tid >> 6;
  const int wr = w >> 1, wc = w & 1;
  const int n15 = lane & 15, quad = lane >> 4;

  const int lrow = lane >> 2;
  const int lseg = (lane & 3) * 8;

  floatx4 acc[4][4] = {};

  for (int k0 = 0; k0 < D_; k0 += 32) {
#pragma unroll
    for (int c = 0; c < 2; c++) {
      int r0 = w * 32 + c * 16;
      int row = r0 + lrow;
      int gm = mbase + row; if (gm > NTOK - 1) gm = NTOK - 1;
      GLD16(ctx + (size_t)gm * D_ + k0 + lseg, Ash + r0 * 32);
      GLD16(wo + (size_t)(nbase + row) * D_ + k0 + lseg, Bsh + r0 * 32);
    }
    __syncthreads();
    bf16x8 af[4], bfr[4];
#pragma unroll
    for (int i = 0; i < 4; i++) {
      af[i]  = *reinterpret_cast<const bf16x8*>(Ash + (wr * 64 + i * 16 + n15) * 32 + quad * 8);
      bfr[i] = *reinterpret_cast<const bf16x8*>(Bsh + (wc * 64 + i * 16 + n15) * 32 + quad * 8);
    }
#pragma unroll
    for (int i = 0; i < 4; i++)
#pragma unroll
      for (int j = 0; j < 4; j++)
        acc[i][j] = __builtin_amdgcn_mfma_f32_16x16x32_bf16(af[i], bfr[j], acc[i][j], 0, 0, 0);
    __syncthreads();
  }

#pragma unroll
  for (int i = 0; i < 4; i++) {
    int rowb = mbase + wr * 64 + i * 16 + quad * 4;
#pragma unroll
    for (int j = 0; j < 4; j++) {
      int col = nbase + wc * 64 + j * 16 + n15;
      float bval = bo[col];
#pragma unroll
      for (int r = 0; r < 4; r++) {
        int m = rowb + r;
        if (m < NTOK) out[(size_t)m * D_ + col] = acc[i][j][r] + bval;
      }
    }
  }
}

extern "C" void kernel_launch(void* const* d_in, const int* in_sizes, int n_in,
                              void* d_out, int out_size, void* d_ws, size_t ws_size,
                              hipStream_t stream) {
  const float* hs = (const float*)d_in[0];
  const float* Wq = (const float*)d_in[1];
  const float* bq = (const float*)d_in[2];
  const float* Wk = (const float*)d_in[3];
  const float* bk = (const float*)d_in[4];
  const float* Wv = (const float*)d_in[5];
  const float* bv = (const float*)d_in[6];
  const float* Wo = (const float*)d_in[7];
  const float* bo = (const float*)d_in[8];

  char* ws = (char*)d_ws;
  bf16* xb   = (bf16*)(ws + OFF_XB);
  bf16* wqkv = (bf16*)(ws + OFF_WQKV);
  bf16* wob  = (bf16*)(ws + OFF_WO);
  bf16* Qfw  = (bf16*)(ws + OFF_Q);
  bf16* Kfw  = (bf16*)(ws + OFF_K);
  bf16* Vfw  = (bf16*)(ws + OFF_V);
  bf16* ctx  = (bf16*)(ws + OFF_CTX);

  cast_bf16_kernel<<<2048, 256, 0, stream>>>(hs, xb, NTOK * D_ / 4);
  cast4_kernel<<<dim3(256, 4), 256, 0, stream>>>(
      Wq, Wk, Wv, Wo,
      wqkv, wqkv + (size_t)D_ * D_, wqkv + (size_t)2 * D_ * D_, wob,
      D_ * D_ / 4);

  qkv_gemm<<<1560, 256, 0, stream>>>(xb, wqkv, bq, bk, bv, Qfw, Kfw, Vfw);
  attn_kernel<<<BH_, 256, 0, stream>>>(Qfw, Kfw, Vfw, ctx);
  o_gemm<<<520, 256, 0, stream>>>(ctx, wob, bo, (float*)d_out);
}

// Round 4
// 252.072 us; speedup vs baseline: 1.4109x; 1.0714x over previous
//
#include <hip/hip_runtime.h>

// ChineseCLIP vision attention, MI355X bf16-MFMA pipeline. Round 4:
//  - attn: K/V staged to LDS (69.6KB) once per bh-block via global_load_lds;
//    all fragment reads become ds_read_b128; V layout packs dt-pairs so one
//    b128 read feeds two PV MFMAs. Zero global re-reads in the S/PV loops.
//  - qkv: epilogue rewritten as LDS transpose (stride-72 rows, 16B aligned)
//    + fully coalesced 16B/lane frag-major stores (1KB contiguous per wave).
// B=32, T=257, D=1024, H=16, HD=64.

#define B_   32
#define T_   257
#define TP   272
#define H_   16
#define HD_  64
#define D_   1024
#define NTOK 8224
#define BH_  512
#define FRAG_PER_BH 17408   // TP*HD elements per (b,h) in frag-major arrays

typedef __bf16 bf16;
typedef __bf16 bf16x4 __attribute__((ext_vector_type(4)));
typedef __bf16 bf16x8 __attribute__((ext_vector_type(8)));
typedef short  s16x4  __attribute__((ext_vector_type(4)));
typedef short  s16x8  __attribute__((ext_vector_type(8)));
typedef float  floatx4 __attribute__((ext_vector_type(4)));

static constexpr size_t SZ_XB   = (size_t)NTOK * D_ * 2;
static constexpr size_t SZ_WQKV = (size_t)3 * D_ * D_ * 2;
static constexpr size_t SZ_W    = (size_t)D_ * D_ * 2;
static constexpr size_t SZ_QK   = (size_t)BH_ * FRAG_PER_BH * 2;

static constexpr size_t OFF_XB   = 0;
static constexpr size_t OFF_WQKV = OFF_XB + SZ_XB;
static constexpr size_t OFF_WO   = OFF_WQKV + SZ_WQKV;
static constexpr size_t OFF_Q    = OFF_WO + SZ_W;
static constexpr size_t OFF_K    = OFF_Q + SZ_QK;
static constexpr size_t OFF_V    = OFF_K + SZ_QK;
static constexpr size_t OFF_CTX  = OFF_V + SZ_QK;

#define GLD16(gp, lp)                                                        \
  __builtin_amdgcn_global_load_lds(                                          \
      (const __attribute__((address_space(1))) void*)(gp),                   \
      (__attribute__((address_space(3))) void*)(lp), 16, 0, 0)

// ---------------- fp32 -> bf16 casts ----------------
__global__ void cast_bf16_kernel(const float* __restrict__ src,
                                 bf16* __restrict__ dst, int n4) {
  int i = blockIdx.x * blockDim.x + threadIdx.x;
  int stride = gridDim.x * blockDim.x;
  for (int idx = i; idx < n4; idx += stride) {
    float4 v = reinterpret_cast<const float4*>(src)[idx];
    bf16x4 o;
    o[0] = (bf16)v.x; o[1] = (bf16)v.y; o[2] = (bf16)v.z; o[3] = (bf16)v.w;
    reinterpret_cast<bf16x4*>(dst)[idx] = o;
  }
}

__global__ void cast4_kernel(const float* __restrict__ s0, const float* __restrict__ s1,
                             const float* __restrict__ s2, const float* __restrict__ s3,
                             bf16* __restrict__ d0, bf16* __restrict__ d1,
                             bf16* __restrict__ d2, bf16* __restrict__ d3, int n4) {
  const float* s = (blockIdx.y == 0) ? s0 : (blockIdx.y == 1) ? s1
                   : (blockIdx.y == 2) ? s2 : s3;
  bf16* d = (blockIdx.y == 0) ? d0 : (blockIdx.y == 1) ? d1
            : (blockIdx.y == 2) ? d2 : d3;
  int i = blockIdx.x * blockDim.x + threadIdx.x;
  int stride = gridDim.x * blockDim.x;
  for (int idx = i; idx < n4; idx += stride) {
    float4 v = reinterpret_cast<const float4*>(s)[idx];
    bf16x4 o;
    o[0] = (bf16)v.x; o[1] = (bf16)v.y; o[2] = (bf16)v.z; o[3] = (bf16)v.w;
    reinterpret_cast<bf16x4*>(d)[idx] = o;
  }
}

// Frag-major layouts (element offsets within one bh's 17408 elems):
// Q/K (A/B-op of 16x16x32): [kt(17)][dc(8)][ki(16)][8]  (t=kt*16+ki, d=dc*8+e)
// V   (A-op of 16x16x16, dt-paired): [kt(17)][p(2)][q2(4)][d16(16)][dp(2)][ki(4)]
//     t = kt*16 + q2*4 + ki, d = p*32 + dp*16 + d16.

// ---------------- fused QKV GEMM ----------------
// grid 1560; swizzle: XCD x owns n-tiles {3x..3x+2}; mbase = linear/24.
__global__ __launch_bounds__(256) void qkv_gemm(
    const bf16* __restrict__ xb, const bf16* __restrict__ wqkv,
    const float* __restrict__ bq, const float* __restrict__ bk,
    const float* __restrict__ bv,
    bf16* __restrict__ Qf, bf16* __restrict__ Kf, bf16* __restrict__ Vf) {
  __shared__ bf16 smem[9216];          // K-loop: Ash(4096)+Bsh(4096); epi: 128x72
  bf16* Ash = smem;
  bf16* Bsh = smem + 4096;

  const int linear = blockIdx.x;
  const int nbg = ((linear & 7) * 3 + ((linear >> 3) % 3)) * 128;
  const int mbase = (linear / 24) * 128;
  const int tid = threadIdx.x;
  const int lane = tid & 63;
  const int w = tid >> 6;
  const int wr = w >> 1, wc = w & 1;
  const int n15 = lane & 15, quad = lane >> 4;

  const int lrow = lane >> 2;
  const int lseg = (lane & 3) * 8;

  floatx4 acc[4][4] = {};

  for (int k0 = 0; k0 < D_; k0 += 32) {
#pragma unroll
    for (int c = 0; c < 2; c++) {
      int r0 = w * 32 + c * 16;
      int row = r0 + lrow;
      int gm = mbase + row; if (gm > NTOK - 1) gm = NTOK - 1;
      GLD16(xb + (size_t)gm * D_ + k0 + lseg, Ash + r0 * 32);
      GLD16(wqkv + (size_t)(nbg + row) * D_ + k0 + lseg, Bsh + r0 * 32);
    }
    __syncthreads();
    bf16x8 af[4], bfr[4];
#pragma unroll
    for (int i = 0; i < 4; i++) {
      af[i]  = *reinterpret_cast<const bf16x8*>(Ash + (wr * 64 + i * 16 + n15) * 32 + quad * 8);
      bfr[i] = *reinterpret_cast<const bf16x8*>(Bsh + (wc * 64 + i * 16 + n15) * 32 + quad * 8);
    }
#pragma unroll
    for (int i = 0; i < 4; i++)
#pragma unroll
      for (int j = 0; j < 4; j++)
        acc[i][j] = __builtin_amdgcn_mfma_f32_16x16x32_bf16(af[i], bfr[j], acc[i][j], 0, 0, 0);
    __syncthreads();
  }

  // ---- epilogue: LDS transpose + coalesced frag-major stores ----
  const int z = nbg >> 10;
  bf16* zdst = (z == 0) ? Qf : (z == 1) ? Kf : Vf;
  const float scale = (z == 0) ? 0.125f : 1.0f;
  const float* bias = (z == 0) ? bq : (z == 1) ? bk : bv;
  const int zoff = nbg & 1023;

  const int bA = mbase / T_;
  const int tA = mbase - bA * T_;
  const int tEndA = (tA + 128 < T_) ? tA + 128 : T_;
  const int tgA0 = tA >> 4;
  const int nA = ((tEndA - 1) >> 4) - tgA0 + 1;
  int nU = nA, tEndB = 0;
  if (tA + 128 > T_ && bA + 1 < B_) {
    tEndB = tA + 128 - T_;
    nU += ((tEndB - 1) >> 4) + 1;
  }

  for (int half = 0; half < 2; half++) {
    if (wc == half) {
#pragma unroll
      for (int i = 0; i < 4; i++)
#pragma unroll
        for (int j = 0; j < 4; j++) {
          int colL = j * 16 + n15;
          float bval = bias[zoff + half * 64 + colL];
#pragma unroll
          for (int r = 0; r < 4; r++) {
            int rowL = wr * 64 + i * 16 + quad * 4 + r;
            smem[rowL * 72 + colL] = (bf16)((acc[i][j][r] + bval) * scale);
          }
        }
    }
    __syncthreads();
    const int h = (zoff >> 6) + half;
    for (int u = w; u < nU; u += 4) {
      int b, tg, tlo, thi;
      if (u < nA) {
        b = bA; tg = tgA0 + u;
        tlo = (tA > tg * 16) ? tA : tg * 16;
        int te = tg * 16 + 16; thi = (te < tEndA) ? te : tEndA;
      } else {
        b = bA + 1; tg = u - nA;
        tlo = tg * 16;
        int te = tg * 16 + 16; thi = (te < tEndB) ? te : tEndB;
      }
      bf16* gb = zdst + (size_t)(b * H_ + h) * FRAG_PER_BH + tg * 1024;
      if (z != 2) {
        int ki = lane & 15, dc = lane >> 4;
        int t = tg * 16 + ki;
        if (t >= tlo && t < thi) {
          int rowL = b * T_ + t - mbase;
          bf16x8 v0 = *reinterpret_cast<const bf16x8*>(smem + rowL * 72 + dc * 8);
          bf16x8 v1 = *reinterpret_cast<const bf16x8*>(smem + rowL * 72 + 32 + dc * 8);
          *reinterpret_cast<bf16x8*>(gb + dc * 128 + ki * 8) = v0;
          *reinterpret_cast<bf16x8*>(gb + 512 + dc * 128 + ki * 8) = v1;
        }
      } else {
        int q2 = (lane >> 4) & 3, d16 = lane & 15;
        int tb = tg * 16 + q2 * 4;
        bool full = (tb >= tlo) && (tb + 3 < thi);
#pragma unroll
        for (int p = 0; p < 2; p++) {
          bf16x8 vv;
#pragma unroll
          for (int dp = 0; dp < 2; dp++)
#pragma unroll
            for (int ki = 0; ki < 4; ki++) {
              int t = tb + ki;
              int rr = (b * T_ + t - mbase) & 127;   // safe for masked elems
              vv[dp * 4 + ki] = smem[rr * 72 + p * 32 + dp * 16 + d16];
            }
          bf16* cp = gb + (p * 4 + q2) * 128 + d16 * 8;
          if (full) {
            *reinterpret_cast<bf16x8*>(cp) = vv;
          } else {
#pragma unroll
            for (int dp = 0; dp < 2; dp++)
#pragma unroll
              for (int ki = 0; ki < 4; ki++) {
                int t = tb + ki;
                if (t >= tlo && t < thi) cp[dp * 4 + ki] = vv[dp * 4 + ki];
              }
          }
        }
      }
    }
    __syncthreads();
  }
}

// ---------------- fused attention (LDS-staged K/V) ----------------
// grid = 512 (one block per bh), 4 waves; wave w handles q-tiles w, w+4, ...
__global__ __launch_bounds__(256) void attn_kernel(
    const bf16* __restrict__ Qf, const bf16* __restrict__ Kf,
    const bf16* __restrict__ Vf, bf16* __restrict__ ctx) {
  __shared__ bf16 smem[34816];   // K (17408) then V (17408)

  const int bh = blockIdx.x;
  const int tid = threadIdx.x;
  const int lane = tid & 63, w = tid >> 6;
  const int n15 = lane & 15, quad = lane >> 4;
  const int b = bh >> 4, h = bh & 15;

  const bf16* Qb = Qf + (size_t)bh * FRAG_PER_BH;
  const bf16* Kb = Kf + (size_t)bh * FRAG_PER_BH;
  const bf16* Vb = Vf + (size_t)bh * FRAG_PER_BH;

  // stage K and V: 68 chunks of 1KB, 17 per wave
#pragma unroll
  for (int j = 0; j < 17; j++) {
    int c = w * 17 + j;
    const bf16* src = (c < 34) ? (Kb + c * 512) : (Vb + (c - 34) * 512);
    GLD16(src + lane * 8, smem + c * 512);
  }
  __syncthreads();
  const bf16* Ksh = smem;
  const bf16* Vsh = smem + 17408;

  const int fo = quad * 128 + n15 * 8;

  for (int qt = w; qt < 17; qt += 4) {
    bf16x8 qb0 = *reinterpret_cast<const bf16x8*>(Qb + qt * 1024 + fo);
    bf16x8 qb1 = *reinterpret_cast<const bf16x8*>(Qb + qt * 1024 + 512 + fo);

    floatx4 s[17];
#pragma unroll
    for (int kt = 0; kt < 17; kt++) {
      bf16x8 ka0 = *reinterpret_cast<const bf16x8*>(Ksh + kt * 1024 + fo);
      bf16x8 ka1 = *reinterpret_cast<const bf16x8*>(Ksh + kt * 1024 + 512 + fo);
      floatx4 c = {};
      c = __builtin_amdgcn_mfma_f32_16x16x32_bf16(ka0, qb0, c, 0, 0, 0);
      c = __builtin_amdgcn_mfma_f32_16x16x32_bf16(ka1, qb1, c, 0, 0, 0);
      s[kt] = c;
    }
    // keys 257..271 invalid: tile 16 holds keys 256+quad*4+r; only 256 valid
    s[16][1] = -1e30f; s[16][2] = -1e30f; s[16][3] = -1e30f;
    if (quad != 0) s[16][0] = -1e30f;

    float m0 = -1e30f;
#pragma unroll
    for (int kt = 0; kt < 17; kt++)
#pragma unroll
      for (int r = 0; r < 4; r++) m0 = fmaxf(m0, s[kt][r]);
    m0 = fmaxf(m0, __shfl_xor(m0, 16));
    m0 = fmaxf(m0, __shfl_xor(m0, 32));

    float sum = 0.f;
    s16x4 pb[17];
#pragma unroll
    for (int kt = 0; kt < 17; kt++) {
      bf16x4 ph;
#pragma unroll
      for (int r = 0; r < 4; r++) {
        float p = __expf(s[kt][r] - m0);
        sum += p;
        ph[r] = (bf16)p;
      }
      pb[kt] = __builtin_bit_cast(s16x4, ph);
    }
    sum += __shfl_xor(sum, 16);
    sum += __shfl_xor(sum, 32);

    floatx4 o[4] = {};
#pragma unroll
    for (int kt = 0; kt < 17; kt++) {
#pragma unroll
      for (int p = 0; p < 2; p++) {
        bf16x8 vv = *reinterpret_cast<const bf16x8*>(
            Vsh + ((kt * 2 + p) * 4 + quad) * 128 + n15 * 8);
        s16x8 v16 = __builtin_bit_cast(s16x8, vv);
        s16x4 vlo = __builtin_shufflevector(v16, v16, 0, 1, 2, 3);
        s16x4 vhi = __builtin_shufflevector(v16, v16, 4, 5, 6, 7);
        o[p * 2]     = __builtin_amdgcn_mfma_f32_16x16x16bf16_1k(vlo, pb[kt], o[p * 2], 0, 0, 0);
        o[p * 2 + 1] = __builtin_amdgcn_mfma_f32_16x16x16bf16_1k(vhi, pb[kt], o[p * 2 + 1], 0, 0, 0);
      }
    }

    int q = qt * 16 + n15;
    if (q < T_) {
      float inv = 1.0f / sum;
      size_t ob = ((size_t)(b * T_ + q)) * D_ + h * 64 + quad * 4;
#pragma unroll
      for (int dt = 0; dt < 4; dt++) {
        bf16x4 ov;
#pragma unroll
        for (int r = 0; r < 4; r++) ov[r] = (bf16)(o[dt][r] * inv);
        *reinterpret_cast<bf16x4*>(ctx + ob + dt * 16) = ov;
      }
    }
  }
}

// ---------------- output projection GEMM (fp32 out) ----------------
__global__ __launch_bounds__(256) void o_gemm(
    const bf16* __restrict__ ctx, const bf16* __restrict__ wo,
    const float* __restrict__ bo, float* __restrict__ out) {
  __shared__ bf16 Ash[128 * 32];
  __shared__ bf16 Bsh[128 * 32];

  const int linear = blockIdx.x;
  const int nbase = (linear & 7) * 128;
  const int mbase = (linear >> 3) * 128;
  const int tid = threadIdx.x;
  const int lane = tid & 63;
  const int w = tid >> 6;
  const int wr = w >> 1, wc = w & 1;
  const int n15 = lane & 15, quad = lane >> 4;

  const int lrow = lane >> 2;
  const int lseg = (lane & 3) * 8;

  floatx4 acc[4][4] = {};

  for (int k0 = 0; k0 < D_; k0 += 32) {
#pragma unroll
    for (int c = 0; c < 2; c++) {
      int r0 = w * 32 + c * 16;
      int row = r0 + lrow;
      int gm = mbase + row; if (gm > NTOK - 1) gm = NTOK - 1;
      GLD16(ctx + (size_t)gm * D_ + k0 + lseg, Ash + r0 * 32);
      GLD16(wo + (size_t)(nbase + row) * D_ + k0 + lseg, Bsh + r0 * 32);
    }
    __syncthreads();
    bf16x8 af[4], bfr[4];
#pragma unroll
    for (int i = 0; i < 4; i++) {
      af[i]  = *reinterpret_cast<const bf16x8*>(Ash + (wr * 64 + i * 16 + n15) * 32 + quad * 8);
      bfr[i] = *reinterpret_cast<const bf16x8*>(Bsh + (wc * 64 + i * 16 + n15) * 32 + quad * 8);
    }
#pragma unroll
    for (int i = 0; i < 4; i++)
#pragma unroll
      for (int j = 0; j < 4; j++)
        acc[i][j] = __builtin_amdgcn_mfma_f32_16x16x32_bf16(af[i], bfr[j], acc[i][j], 0, 0, 0);
    __syncthreads();
  }

#pragma unroll
  for (int i = 0; i < 4; i++) {
    int rowb = mbase + wr * 64 + i * 16 + quad * 4;
#pragma unroll
    for (int j = 0; j < 4; j++) {
      int col = nbase + wc * 64 + j * 16 + n15;
      float bval = bo[col];
#pragma unroll
      for (int r = 0; r < 4; r++) {
        int m = rowb + r;
        if (m < NTOK) out[(size_t)m * D_ + col] = acc[i][j][r] + bval;
      }
    }
  }
}

extern "C" void kernel_launch(void* const* d_in, const int* in_sizes, int n_in,
                              void* d_out, int out_size, void* d_ws, size_t ws_size,
                              hipStream_t stream) {
  const float* hs = (const float*)d_in[0];
  const float* Wq = (const float*)d_in[1];
  const float* bq = (const float*)d_in[2];
  const float* Wk = (const float*)d_in[3];
  const float* bk = (const float*)d_in[4];
  const float* Wv = (const float*)d_in[5];
  const float* bv = (const float*)d_in[6];
  const float* Wo = (const float*)d_in[7];
  const float* bo = (const float*)d_in[8];

  char* ws = (char*)d_ws;
  bf16* xb   = (bf16*)(ws + OFF_XB);
  bf16* wqkv = (bf16*)(ws + OFF_WQKV);
  bf16* wob  = (bf16*)(ws + OFF_WO);
  bf16* Qfw  = (bf16*)(ws + OFF_Q);
  bf16* Kfw  = (bf16*)(ws + OFF_K);
  bf16* Vfw  = (bf16*)(ws + OFF_V);
  bf16* ctx  = (bf16*)(ws + OFF_CTX);

  cast_bf16_kernel<<<2048, 256, 0, stream>>>(hs, xb, NTOK * D_ / 4);
  cast4_kernel<<<dim3(256, 4), 256, 0, stream>>>(
      Wq, Wk, Wv, Wo,
      wqkv, wqkv + (size_t)D_ * D_, wqkv + (size_t)2 * D_ * D_, wob,
      D_ * D_ / 4);

  qkv_gemm<<<1560, 256, 0, stream>>>(xb, wqkv, bq, bk, bv, Qfw, Kfw, Vfw);
  attn_kernel<<<BH_, 256, 0, stream>>>(Qfw, Kfw, Vfw, ctx);
  o_gemm<<<520, 256, 0, stream>>>(ctx, wob, bo, (float*)d_out);
}